// Round 6
// baseline (37.523 us; speedup 1.0000x reference)
//
#include <hip/hip_runtime.h>
#include <math.h>

// B=256, K=51, N=8192. out = MULT * sum_{b,d} sqrt(w_b^T G_d w_b),
// w = y_hat - y, G_d[k1,k2] = sum_n bs[k1,n,d]*bs[k2,n,d].
// (face cancels; EPS cross-term ~1e-6 relative -> dropped, validated earlier.)
//
// Round 6: collapse the K1->K2 dispatch boundary. One fat dispatch of 348
// blocks (192 gram + 156 finalize) ordered by the session-proven release-
// ticket + relaxed agent-scope (LLC-direct) load pattern -- no spin-with-
// acquire (round-1 lesson), no L2 invalidates in the hot path. A 1-block
// init kernel precedes it (pq/ctr must be re-zeroed every iteration since
// the harness re-poisons d_ws).
//   gram blocks (bx<192): champion K1 core verbatim; after C-write,
//     __syncthreads (drains stores per-wave) then RELEASE fetch_add(ctr).
//   fin blocks (bx>=192): champion K2 verbatim except (a) w-staging first
//     (overlaps gram phase), (b) tid0 polls ctr>=192 with RELAXED agent
//     loads + s_sleep (no acquire -> no inv), (c) Phase R reads partial via
//     RELAXED agent loads -- same latency class as champion (those loads
//     missed L2 anyway: written by other XCDs), but stale-proof w/o fences.
//   Deadlock-free by capacity: 18.5KB LDS, ~128 VGPR -> >=4 blocks/CU ->
//   all 348 co-resident on 256 CUs; gram always progresses.
// All FP operations and their order are bit-identical to the champion.
#define NPTS     8192
#define KDIM     51
#define KPAD     64
#define CHUNKS   64
#define CHUNK_N  128
#define MULT     0.0025f
#define GBLK     192            // gram blocks: 3 d x 64 chunks
#define FBLK     156            // finalize blocks: 3 d x 13 rg x 4 bg
#define TBLK     (GBLK + FBLK)  // 348

typedef short short8  __attribute__((ext_vector_type(8)));
typedef float float4v __attribute__((ext_vector_type(4)));
// dword-aligned (NOT 16B) float4 for the staging trick below
typedef float float4a __attribute__((ext_vector_type(4), aligned(4)));

// RNE f32 -> bf16 bits (inputs are normal floats; NaN path irrelevant)
__device__ __forceinline__ unsigned short f32_to_bf16(float f) {
    unsigned int u = __float_as_uint(f);
    unsigned int r = u + 0x7FFFu + ((u >> 16) & 1u);
    return (unsigned short)(r >> 16);
}

// ---------------------------------------------------------------------------
// Init: pq[768]=0, ctr=0. Runs as its own tiny dispatch so the fat kernel's
// LLC atomics see clean state (kernel-boundary visibility).
// ---------------------------------------------------------------------------
__global__ __launch_bounds__(256) void pl_init(float* __restrict__ pq,
                                               unsigned int* __restrict__ ctr) {
  const int tid = threadIdx.x;
  pq[tid] = 0.0f; pq[256 + tid] = 0.0f; pq[512 + tid] = 0.0f;
  if (tid == 0) ctr[0] = 0u;
}

// ---------------------------------------------------------------------------
// Fused kernel. LDS overlaid: gram path uses smem as lds16[64*136] (17408B);
// fin path as Gl[256] (1024B) + wl[64*68] (17408B) = 18432B.
//
// Gram core (champion, HW-verified layouts per guide §3):
//   LDS lds16[shape][point], stride 136 bf16; 4 waves own 32x32 quadrants as
//   2x2 16x16 tiles; K-loop 4 iters of K=32 points.
//   A: m=lane&15, k=(lane>>4)*8+j   B: mirror   C: col=lane&15, row=(lane>>4)*4+reg
// ---------------------------------------------------------------------------
__global__ __launch_bounds__(256) void pl_fused(
    const float* __restrict__ bs, float* __restrict__ partial,
    float* __restrict__ pq, unsigned int* __restrict__ ctr,
    const float* __restrict__ yh, const float* __restrict__ yv,
    float* __restrict__ out) {
  __shared__ __align__(16) char smem[18448];
  __shared__ unsigned int lflag;
  __shared__ float redw[4];

  const int bx  = blockIdx.x;
  const int tid = threadIdx.x;

  if (bx < GBLK) {
    // ---------------- gram path (champion K1 core, verbatim) ----------------
    unsigned short* lds16 = (unsigned short*)smem;
    const int d  = bx / CHUNKS;
    const int n0 = (bx % CHUNKS) * CHUNK_N;

    // Stage: u -> (shape k = u>>6, point-pair np = u&63). Lanes: np
    // consecutive, k fixed -> LDS banks (4k+np)%32 = all 32, 2-way (free).
    // One dword-aligned dwordx4 covers both points (elements 0 and 3); last
    // pair's element 3 is exactly the final bs element: no OOB. d-sibling
    // blocks (bx+-64, same XCD under %8 mapping) reuse the cache lines.
    unsigned int* lds32 = (unsigned int*)lds16;
    for (int u = tid; u < KPAD * (CHUNK_N / 2); u += 256) {
      int np = u & 63;
      int k  = u >> 6;
      float v0 = 0.0f, v1 = 0.0f;
      if (k < KDIM) {
        const float* p = bs + (size_t)k * (NPTS * 3) + (size_t)(n0 + 2 * np) * 3 + d;
        float4a f = *(const float4a*)p;
        v0 = f[0];
        v1 = f[3];
      }
      lds32[k * 68 + np] = (unsigned int)f32_to_bf16(v0) |
                           ((unsigned int)f32_to_bf16(v1) << 16);
    }
    __syncthreads();

    const int wave  = tid >> 6;
    const int lane  = tid & 63;
    const int m16   = lane & 15;
    const int quad  = lane >> 4;
    const int rbase = (wave >> 1) * 32;
    const int cbase = (wave & 1) * 32;

    float4v acc00 = {0.f, 0.f, 0.f, 0.f}, acc01 = {0.f, 0.f, 0.f, 0.f};
    float4v acc10 = {0.f, 0.f, 0.f, 0.f}, acc11 = {0.f, 0.f, 0.f, 0.f};

#pragma unroll
    for (int p0 = 0; p0 < CHUNK_N; p0 += 32) {
      const int po = p0 + quad * 8;
      short8 a0 = *(const short8*)&lds16[(rbase +      m16) * 136 + po];
      short8 a1 = *(const short8*)&lds16[(rbase + 16 + m16) * 136 + po];
      short8 b0 = *(const short8*)&lds16[(cbase +      m16) * 136 + po];
      short8 b1 = *(const short8*)&lds16[(cbase + 16 + m16) * 136 + po];
      acc00 = __builtin_amdgcn_mfma_f32_16x16x32_bf16(a0, b0, acc00, 0, 0, 0);
      acc01 = __builtin_amdgcn_mfma_f32_16x16x32_bf16(a0, b1, acc01, 0, 0, 0);
      acc10 = __builtin_amdgcn_mfma_f32_16x16x32_bf16(a1, b0, acc10, 0, 0, 0);
      acc11 = __builtin_amdgcn_mfma_f32_16x16x32_bf16(a1, b1, acc11, 0, 0, 0);
    }

    // Emit in NATURAL [row][col] layout. Shapes >=51 are zero-padded ->
    // rows/cols >=51 hold exact zeros (valid to reduce downstream).
    float* pout = partial + (size_t)bx * 4096;
#pragma unroll
    for (int r = 0; r < 4; ++r) {
      int row0 = rbase + quad * 4 + r;
      int col0 = cbase + m16;
      pout[row0 * 64 + col0]               = acc00[r];
      pout[row0 * 64 + (col0 + 16)]        = acc01[r];
      pout[(row0 + 16) * 64 + col0]        = acc10[r];
      pout[(row0 + 16) * 64 + (col0 + 16)] = acc11[r];
    }

    // Publish: barrier drains every wave's stores to L2 (compiler emits
    // vmcnt(0) before s_barrier); RELEASE fetch_add writes the XCD's dirty
    // lines back to LLC, then bumps the ticket. No acquire, no spin.
    __syncthreads();
    if (tid == 0)
      __hip_atomic_fetch_add(ctr, 1u, __ATOMIC_RELEASE,
                             __HIP_MEMORY_SCOPE_AGENT);
    return;
  }

  // ---------------- finalize path (champion K2, re-ordered W first) --------
  float* Gl = (float*)smem;             // 256 floats
  float* wl = (float*)(smem + 1024);    // 64*68 floats

  const int fx  = bx - GBLK;            // 156 = 3 d x 13 rg x 4 bg
  const int d   = fx / 52;
  const int rem = fx - d * 52;
  const int rg  = rem >> 2;
  const int b0  = (rem & 3) * 64;

  // Phase W first: overlaps the gram phase. Cols 51..63 zeroed (zero-padded
  // G rows/cols then contribute exact 0, never 0*poison).
  for (int i = tid; i < 64 * KDIM; i += 256) {
    int bl = i / KDIM, k = i - bl * KDIM;
    int gi = (b0 + bl) * KDIM + k;
    wl[bl * 68 + k] = yh[gi] - yv[gi];
  }
  for (int i = tid; i < 64 * 13; i += 256) {
    int bl = i / 13, c = KDIM + (i - bl * 13);
    wl[bl * 68 + c] = 0.0f;
  }

  // Wait for all gram releases. RELAXED agent loads hit the LLC (coherence
  // point) -- no acquire, no L2 invalidate, just a read poll with sleep.
  if (tid == 0) {
    while (__hip_atomic_load(ctr, __ATOMIC_RELAXED,
                             __HIP_MEMORY_SCOPE_AGENT) < (unsigned)GBLK)
      __builtin_amdgcn_s_sleep(8);
  }
  __syncthreads();

  // Phase R: reduce my 4 Gram rows (256 consecutive floats at rg*256), same
  // serial c-order as champion (bit-identical sums). Agent-scope loads go
  // LLC-direct: same latency class as champion's L2-missing plain loads,
  // but immune to stale local-L2 lines without any fence.
  {
    const float* p = partial + (size_t)(d * CHUNKS) * 4096 + rg * 256 + tid;
    float s = 0.0f;
#pragma unroll 16
    for (int c = 0; c < CHUNKS; ++c)
      s += __hip_atomic_load(&p[(size_t)c * 4096], __ATOMIC_RELAXED,
                             __HIP_MEMORY_SCOPE_AGENT);
    Gl[tid] = s;
  }
  __syncthreads();

  // Phase C (champion verbatim): thread (jt=tid&15, bh=tid>>4); 4 G-row
  // float4s hoisted to regs; per bl: t[ri] = G_row[ri][strip jt].w[strip jt],
  // pqp = sum_ri w[b][rg*4+ri]*t[ri]; shfl-reduce over 16 jt lanes; jt==0
  // atomicAdd(pq[d*256+b]) (device scope = LLC, fence-free).
  {
    const int jt = tid & 15;
    const int bh = tid >> 4;
    float4v g4[4];
#pragma unroll
    for (int ri = 0; ri < 4; ++ri)
      g4[ri] = *(const float4v*)&Gl[ri * 64 + jt * 4];

#pragma unroll
    for (int bl = 0; bl < 4; ++bl) {
      const int lb = bl * 16 + bh;
      float4v wj = *(const float4v*)&wl[lb * 68 + jt * 4];
      float4v wk = *(const float4v*)&wl[lb * 68 + rg * 4];
      float pqp = 0.0f;
#pragma unroll
      for (int ri = 0; ri < 4; ++ri) {
        float t = 0.0f;
#pragma unroll
        for (int jj = 0; jj < 4; ++jj) t = fmaf(g4[ri][jj], wj[jj], t);
        pqp = fmaf(wk[ri], t, pqp);
      }
#pragma unroll
      for (int off = 1; off < 16; off <<= 1) pqp += __shfl_xor(pqp, off, 16);
      if (jt == 0) atomicAdd(&pq[d * 256 + b0 + lb], pqp);
    }
  }
  __syncthreads();   // drains each wave's outstanding atomics before release

  if (tid == 0) {
    unsigned int old = __hip_atomic_fetch_add(ctr, 1u, __ATOMIC_RELEASE,
                                              __HIP_MEMORY_SCOPE_AGENT);
    lflag = (old == (TBLK - 1)) ? 1u : 0u;
  }
  __syncthreads();
  if (lflag == 0u) return;   // all but the last finisher exit; no spin here

  // Last finisher: single acquire, then sqrt-sum of all 768 q values.
  if (tid == 0)
    (void)__hip_atomic_load(ctr, __ATOMIC_ACQUIRE, __HIP_MEMORY_SCOPE_AGENT);
  __syncthreads();

  float s = 0.0f;
#pragma unroll
  for (int i = 0; i < 3; ++i) {
    // Agent-scope loads: pq values live at the LLC (written by atomics);
    // final once ctr hit TBLK.
    float q = __hip_atomic_load(&pq[i * 256 + tid], __ATOMIC_RELAXED,
                                __HIP_MEMORY_SCOPE_AGENT);
    s += sqrtf(q);
  }
  for (int off = 32; off; off >>= 1) s += __shfl_down(s, off, 64);
  if ((tid & 63) == 0) redw[tid >> 6] = s;
  __syncthreads();
  if (tid == 0)
    out[0] = (redw[0] + redw[1] + redw[2] + redw[3]) * MULT;
}

extern "C" void kernel_launch(void* const* d_in, const int* in_sizes, int n_in,
                              void* d_out, int out_size, void* d_ws, size_t ws_size,
                              hipStream_t stream) {
  const float* y_hat = (const float*)d_in[0];   // [256,51]
  const float* y     = (const float*)d_in[1];   // [256,51]
  // d_in[2] = face [8192,3] — cancels algebraically, unused
  const float* bs    = (const float*)d_in[3];   // [51,8192,3]
  float* out = (float*)d_out;

  float* partial    = (float*)d_ws;                          // 192*4096 floats
  float* pq         = partial + (size_t)3 * CHUNKS * 4096;   // 768 floats
  unsigned int* ctr = (unsigned int*)(pq + 768);             // 1 uint

  pl_init<<<1, 256, 0, stream>>>(pq, ctr);
  pl_fused<<<TBLK, 256, 0, stream>>>(bs, partial, pq, ctr, y_hat, y, out);
}

// Round 7
// 19.756 us; speedup vs baseline: 1.8993x; 1.8993x over previous
//
#include <hip/hip_runtime.h>
#include <math.h>

// B=256, K=51, N=8192. out = MULT * sum_{b,d} sqrt(w_b^T G_d w_b),
// w = y_hat - y, G_d[k1,k2] = sum_n bs[k1,n,d]*bs[k2,n,d].
// (face cancels; EPS cross-term ~1e-6 relative -> dropped, validated earlier.)
//
// ROUND 7 = CHAMPION (exact round-2 source; 19.43 / 19.52 us in R2/R5).
// Session evidence: every structural alternative regressed -- grid-barrier
// fusion +7 (R1), direct-projection +8 (R3), store/unroll deltas +16 (R4),
// ticket-fused single dispatch +18 (R6; atomic loads bypass wave coalescing
// -> 16x LLC transactions in Phase R, pollers contend with releases).
// This restores the best-known kernel; structure is at its measured floor.
//
// Two dispatches, NO grid-wide barrier (round-1 lesson: all-block
// release+acquire+spin on 8 non-coherent XCD L2s cost +4 us):
//   K1 pl_gram (193 blocks): blocks 0..191 produce per-(d,chunk) partial
//      Grams via MFMA. Block 192 zero-inits pq[768] + ctr (visible to K2 via
//      the kernel boundary).
//   K2 pl_finalize (156 blocks = 3 d x 13 rowgroups x 4 batchgroups):
//      q[b,d] = sum_k1 w[b,k1]*(G_row_k1 . w_b) is ADDITIVE over rowgroups,
//      so each block: reduce its 4 Gram rows over 64 chunks (same serial
//      order as before), compute partial quadratic forms for its 64 batch
//      rows, atomicAdd into pq (device-scope atomics = LLC, fence-free).
//      Completion: per-block RELEASE fetch_add on ctr (few dirty lines ->
//      cheap; no inv, no spin; blocks exit). The block seeing old==155 does
//      ONE acquire and the 768-element sqrt-sum via agent-scope loads
//      (bypass possibly-stale L2 zeros from K1's init), stores out.
#define NPTS     8192
#define KDIM     51
#define KPAD     64
#define CHUNKS   64
#define CHUNK_N  128
#define MULT     0.0025f

typedef short short8  __attribute__((ext_vector_type(8)));
typedef float float4v __attribute__((ext_vector_type(4)));
// dword-aligned (NOT 16B) float4 for the staging trick below
typedef float float4a __attribute__((ext_vector_type(4), aligned(4)));

// RNE f32 -> bf16 bits (inputs are normal floats; NaN path irrelevant)
__device__ __forceinline__ unsigned short f32_to_bf16(float f) {
    unsigned int u = __float_as_uint(f);
    unsigned int r = u + 0x7FFFu + ((u >> 16) & 1u);
    return (unsigned short)(r >> 16);
}

// ---------------------------------------------------------------------------
// Kernel 1: per-(d, 128-point chunk) partial Gram via MFMA bf16.
// LDS: lds16[shape][point], stride 136 bf16 (=68 dwords; 68%32=4 -> rows
// rotate banks, staged pair-writes are 2-way = free). Each of 4 waves owns a
// 32x32 quadrant as 2x2 16x16 tiles; K-loop 4 iters of K=32 points.
// mfma_f32_16x16x32_bf16 layouts (HW-verified, guide §3):
//   A: m=lane&15, k=(lane>>4)*8+j  (8 contiguous points)   B: mirror
//   C: col=lane&15, row=(lane>>4)*4+reg
// G symmetric => robust to A/B role mixups; only k-mapping must match.
// ---------------------------------------------------------------------------
__global__ __launch_bounds__(256) void pl_gram(
    const float* __restrict__ bs, float* __restrict__ partial,
    float* __restrict__ pq, unsigned int* __restrict__ ctr) {
  __shared__ unsigned short lds16[KPAD * 136];

  const int bx  = blockIdx.x;
  const int tid = threadIdx.x;

  // Dedicated init block: zero pq + ctr for K2. Uniform early return (whole
  // block takes this path -> no barrier divergence).
  if (bx == 192) {
    for (int i = tid; i < 768; i += 256) pq[i] = 0.0f;
    if (tid == 0) ctr[0] = 0u;
    return;
  }

  const int d   = bx / CHUNKS;
  const int n0  = (bx % CHUNKS) * CHUNK_N;

  // Stage: u -> (shape k = u>>6, point-pair np = u&63). Lanes: np consecutive,
  // k fixed -> LDS banks (4k+np)%32 = all 32, 2-way (free). Global: one
  // dword-aligned dwordx4 covers both points of the pair (elements 0 and 3:
  // addresses 3n+d and 3(n+1)+d). Last pair's element 3 is exactly the final
  // bs element: no OOB. d-sibling blocks (bx+-64, same XCD under %8 mapping)
  // reuse the cache lines.
  unsigned int* lds32 = (unsigned int*)lds16;
  for (int u = tid; u < KPAD * (CHUNK_N / 2); u += 256) {
    int np = u & 63;
    int k  = u >> 6;
    float v0 = 0.0f, v1 = 0.0f;
    if (k < KDIM) {
      const float* p = bs + (size_t)k * (NPTS * 3) + (size_t)(n0 + 2 * np) * 3 + d;
      float4a f = *(const float4a*)p;
      v0 = f[0];
      v1 = f[3];
    }
    lds32[k * 68 + np] = (unsigned int)f32_to_bf16(v0) |
                         ((unsigned int)f32_to_bf16(v1) << 16);
  }
  __syncthreads();

  const int wave  = tid >> 6;
  const int lane  = tid & 63;
  const int m16   = lane & 15;
  const int quad  = lane >> 4;
  const int rbase = (wave >> 1) * 32;
  const int cbase = (wave & 1) * 32;

  float4v acc00 = {0.f, 0.f, 0.f, 0.f}, acc01 = {0.f, 0.f, 0.f, 0.f};
  float4v acc10 = {0.f, 0.f, 0.f, 0.f}, acc11 = {0.f, 0.f, 0.f, 0.f};

#pragma unroll
  for (int p0 = 0; p0 < CHUNK_N; p0 += 32) {
    const int po = p0 + quad * 8;
    short8 a0 = *(const short8*)&lds16[(rbase +      m16) * 136 + po];
    short8 a1 = *(const short8*)&lds16[(rbase + 16 + m16) * 136 + po];
    short8 b0 = *(const short8*)&lds16[(cbase +      m16) * 136 + po];
    short8 b1 = *(const short8*)&lds16[(cbase + 16 + m16) * 136 + po];
    acc00 = __builtin_amdgcn_mfma_f32_16x16x32_bf16(a0, b0, acc00, 0, 0, 0);
    acc01 = __builtin_amdgcn_mfma_f32_16x16x32_bf16(a0, b1, acc01, 0, 0, 0);
    acc10 = __builtin_amdgcn_mfma_f32_16x16x32_bf16(a1, b0, acc10, 0, 0, 0);
    acc11 = __builtin_amdgcn_mfma_f32_16x16x32_bf16(a1, b1, acc11, 0, 0, 0);
  }

  // Emit in NATURAL [row][col] layout. Shapes >=51 are zero-padded -> rows/
  // cols >=51 hold exact zeros (valid to reduce; keeps K2's j-loop NaN-free).
  float* pout = partial + (size_t)bx * 4096;
#pragma unroll
  for (int r = 0; r < 4; ++r) {
    int row0 = rbase + quad * 4 + r;
    int col0 = cbase + m16;
    pout[row0 * 64 + col0]               = acc00[r];
    pout[row0 * 64 + (col0 + 16)]        = acc01[r];
    pout[(row0 + 16) * 64 + col0]        = acc10[r];
    pout[(row0 + 16) * 64 + (col0 + 16)] = acc11[r];
  }
}

// ---------------------------------------------------------------------------
// Kernel 2: rowgroup-decomposed reduce+finalize. bx -> (d, rg, bg):
//   d = bx/52, rem = bx%52, rg = rem>>2 (rows rg*4..rg*4+3), bg = rem&3
//   (batch rows bg*64..bg*64+63).
// Phase R: Gl[e] (e = ri*64+col) = sum over 64 chunks, serial c-order.
// Phase W: wl[64][68] = y_hat - y for this batch group; cols 51..63 zeroed
//          (zero-padded G rows/cols then contribute exact 0, never 0*poison).
// Phase C: thread (jt=tid&15, bh=tid>>4); 4 G-row float4s hoisted to regs;
//          per bl (4 batch rows): t[ri] = G_row[ri][strip jt] . w[strip jt],
//          pq_part = sum_ri w[b][rg*4+ri]*t[ri]; shfl-reduce over 16 jt
//          lanes; lane 0 atomicAdd(pq[d*256+b]).
// ---------------------------------------------------------------------------
__global__ __launch_bounds__(256) void pl_finalize(
    const float* __restrict__ partial, float* __restrict__ pq,
    unsigned int* __restrict__ ctr, const float* __restrict__ yh,
    const float* __restrict__ yv, float* __restrict__ out) {
  __shared__ __align__(16) float Gl[256];
  __shared__ __align__(16) float wl[64 * 68];
  __shared__ unsigned int lflag;
  __shared__ float redw[4];

  const int bx  = blockIdx.x;
  const int d   = bx / 52;
  const int rem = bx - d * 52;
  const int rg  = rem >> 2;
  const int b0  = (rem & 3) * 64;
  const int tid = threadIdx.x;

  // Phase R: reduce my 4 Gram rows (256 consecutive floats at rg*256).
  {
    const float* p = partial + (size_t)(d * CHUNKS) * 4096 + rg * 256 + tid;
    float s = 0.0f;
#pragma unroll 16
    for (int c = 0; c < CHUNKS; ++c) s += p[(size_t)c * 4096];
    Gl[tid] = s;
  }

  // Phase W: stage w for my 64 batch rows; zero-pad cols 51..63.
  for (int i = tid; i < 64 * KDIM; i += 256) {
    int bl = i / KDIM, k = i - bl * KDIM;
    int gi = (b0 + bl) * KDIM + k;
    wl[bl * 68 + k] = yh[gi] - yv[gi];
  }
  for (int i = tid; i < 64 * 13; i += 256) {
    int bl = i / 13, c = KDIM + (i - bl * 13);
    wl[bl * 68 + c] = 0.0f;
  }
  __syncthreads();

  // Phase C.
  {
    const int jt = tid & 15;
    const int bh = tid >> 4;
    float4v g4[4];
#pragma unroll
    for (int ri = 0; ri < 4; ++ri)
      g4[ri] = *(const float4v*)&Gl[ri * 64 + jt * 4];

#pragma unroll
    for (int bl = 0; bl < 4; ++bl) {
      const int lb = bl * 16 + bh;
      float4v wj = *(const float4v*)&wl[lb * 68 + jt * 4];
      float4v wk = *(const float4v*)&wl[lb * 68 + rg * 4];
      float pqp = 0.0f;
#pragma unroll
      for (int ri = 0; ri < 4; ++ri) {
        float t = 0.0f;
#pragma unroll
        for (int jj = 0; jj < 4; ++jj) t = fmaf(g4[ri][jj], wj[jj], t);
        pqp = fmaf(wk[ri], t, pqp);
      }
#pragma unroll
      for (int off = 1; off < 16; off <<= 1) pqp += __shfl_xor(pqp, off, 16);
      if (jt == 0) atomicAdd(&pq[d * 256 + b0 + lb], pqp);
    }
  }
  __syncthreads();   // drains each wave's outstanding atomics before release

  if (tid == 0) {
    unsigned int old = __hip_atomic_fetch_add(ctr, 1u, __ATOMIC_RELEASE,
                                              __HIP_MEMORY_SCOPE_AGENT);
    lflag = (old == 155u) ? 1u : 0u;
  }
  __syncthreads();
  if (lflag == 0u) return;   // 155 blocks exit immediately; no spin anywhere

  // Last block: single acquire, then sqrt-sum of all 768 q values.
  if (tid == 0)
    (void)__hip_atomic_load(ctr, __ATOMIC_ACQUIRE, __HIP_MEMORY_SCOPE_AGENT);
  __syncthreads();

  float s = 0.0f;
#pragma unroll
  for (int i = 0; i < 3; ++i) {
    // Agent-scope loads bypass L1/L2 (this XCD's L2 may hold stale zeros
    // from K1's init block); values are final once ctr hit 192.
    float q = __hip_atomic_load(&pq[i * 256 + tid], __ATOMIC_RELAXED,
                                __HIP_MEMORY_SCOPE_AGENT);
    s += sqrtf(q);
  }
  for (int off = 32; off; off >>= 1) s += __shfl_down(s, off, 64);
  if ((tid & 63) == 0) redw[tid >> 6] = s;
  __syncthreads();
  if (tid == 0)
    out[0] = (redw[0] + redw[1] + redw[2] + redw[3]) * MULT;
}

extern "C" void kernel_launch(void* const* d_in, const int* in_sizes, int n_in,
                              void* d_out, int out_size, void* d_ws, size_t ws_size,
                              hipStream_t stream) {
  const float* y_hat = (const float*)d_in[0];   // [256,51]
  const float* y     = (const float*)d_in[1];   // [256,51]
  // d_in[2] = face [8192,3] — cancels algebraically, unused
  const float* bs    = (const float*)d_in[3];   // [51,8192,3]
  float* out = (float*)d_out;

  float* partial    = (float*)d_ws;                          // 192*4096 floats
  float* pq         = partial + (size_t)3 * CHUNKS * 4096;   // 768 floats
  unsigned int* ctr = (unsigned int*)(pq + 768);             // 1 uint

  pl_gram<<<3 * CHUNKS + 1, 256, 0, stream>>>(bs, partial, pq, ctr);
  pl_finalize<<<156, 256, 0, stream>>>(partial, pq, ctr, y_hat, y, out);
}